// Round 7
// baseline (226.579 us; speedup 1.0000x reference)
//
#include <hip/hip_runtime.h>
#include <math.h>

#define B_  8
#define H_  8
#define C_  512
#define L_  1024
#define DH  64
#define WIN 4

typedef __attribute__((ext_vector_type(8))) short short8;
typedef __attribute__((ext_vector_type(4))) float floatx4;
typedef __attribute__((ext_vector_type(4))) _Float16 half4_;

__device__ __forceinline__ unsigned short f2bf(float f) {
    unsigned int u = __float_as_uint(f);
    u = u + 0x7FFFu + ((u >> 16) & 1u);     // RNE
    return (unsigned short)(u >> 16);
}
__device__ __forceinline__ float bf2f(unsigned short h) {
    return __uint_as_float(((unsigned int)h) << 16);
}
__device__ __forceinline__ unsigned short f2h(float f) {
    _Float16 h = (_Float16)f;
    return *reinterpret_cast<unsigned short*>(&h);
}

// ---------------------------------------------------------------------------
// prep: Wq/Wk/Wv -> bf16 hi (packed 3x512x512), Wo -> hi+lo, pack biases.
// ---------------------------------------------------------------------------
__global__ __launch_bounds__(256) void prep_kernel(
    const float* __restrict__ Wq, const float* __restrict__ Wk,
    const float* __restrict__ Wv, const float* __restrict__ Wo,
    const float* __restrict__ bq, const float* __restrict__ bk,
    const float* __restrict__ bv,
    unsigned short* __restrict__ Wqkv_hi,
    unsigned short* __restrict__ Wo_hi, unsigned short* __restrict__ Wo_lo,
    float* __restrict__ bqkv)
{
    const int i = blockIdx.x * 256 + threadIdx.x;   // 65536 float4 slots
    float4 v; ushort4 h;

    v = ((const float4*)Wq)[i];
    h.x = f2bf(v.x); h.y = f2bf(v.y); h.z = f2bf(v.z); h.w = f2bf(v.w);
    ((ushort4*)Wqkv_hi)[i] = h;

    v = ((const float4*)Wk)[i];
    h.x = f2bf(v.x); h.y = f2bf(v.y); h.z = f2bf(v.z); h.w = f2bf(v.w);
    ((ushort4*)Wqkv_hi)[65536 + i] = h;

    v = ((const float4*)Wv)[i];
    h.x = f2bf(v.x); h.y = f2bf(v.y); h.z = f2bf(v.z); h.w = f2bf(v.w);
    ((ushort4*)Wqkv_hi)[131072 + i] = h;

    v = ((const float4*)Wo)[i];
    h.x = f2bf(v.x); h.y = f2bf(v.y); h.z = f2bf(v.z); h.w = f2bf(v.w);
    ((ushort4*)Wo_hi)[i] = h;
    ushort4 lo;
    lo.x = f2bf(v.x - bf2f(h.x)); lo.y = f2bf(v.y - bf2f(h.y));
    lo.z = f2bf(v.z - bf2f(h.z)); lo.w = f2bf(v.w - bf2f(h.w));
    ((ushort4*)Wo_lo)[i] = lo;

    if (i < 512)       bqkv[i] = bq[i];
    else if (i < 1024) bqkv[i] = bk[i - 512];
    else if (i < 1536) bqkv[i] = bv[i - 1024];
}

// ---------------------------------------------------------------------------
// x (B,C,L) fp32 -> xT bf16 (B,L,C).  32x32 LDS transpose.
// ---------------------------------------------------------------------------
__global__ __launch_bounds__(256) void transpose_kernel(
    const float* __restrict__ x, unsigned short* __restrict__ xT)
{
    __shared__ float tile[32][33];
    const int b  = blockIdx.z;
    const int cb = blockIdx.y * 32;
    const int lb = blockIdx.x * 32;
    const int t  = threadIdx.x;
    {
        const int l = t & 31, c0 = t >> 5;
#pragma unroll
        for (int p = 0; p < 4; ++p) {
            const int c = c0 + 8 * p;
            tile[c][l] = x[((size_t)b * C_ + cb + c) * L_ + lb + l];
        }
    }
    __syncthreads();
    {
        const int c = t & 31, l0 = t >> 5;
#pragma unroll
        for (int p = 0; p < 4; ++p) {
            const int l = l0 + 8 * p;
            xT[((size_t)b * L_ + lb + l) * C_ + cb + c] = f2bf(tile[c][l]);
        }
    }
}

// ---------------------------------------------------------------------------
// Fused QKV GEMM, plain bf16.  M=1536 x N=1024 x K=512.
// ALL outputs stored coalesced in (B,C,L) order: Q,K as bf16, V as f16.
// (The R6 scattered (B,H,L,Dh) Q/K stores touched 64 lines per wave-store.)
// ---------------------------------------------------------------------------
__global__ __launch_bounds__(256) void qkv_gemm_kernel(
    const unsigned short* __restrict__ Wh, const float* __restrict__ bqkv,
    const unsigned short* __restrict__ xT,
    unsigned short* __restrict__ Qc, unsigned short* __restrict__ Kc,
    unsigned short* __restrict__ Vc)
{
    __shared__ __align__(16) unsigned short As[128][40];
    __shared__ __align__(16) unsigned short Bs[128][40];

    const int b   = blockIdx.z;
    const int oB  = blockIdx.y * 128;
    const int mat = oB >> 9;                // 0=Q,1=K,2=V
    const int ob  = oB & 511;
    const int lb  = blockIdx.x * 128;
    const int t  = threadIdx.x;
    const int w = t >> 6, lane = t & 63, quad = lane >> 4, lc = lane & 15;
    const int wm = w >> 1, wn = w & 1;

    const unsigned short* Wm = Wh + (size_t)mat * C_ * C_;

    floatx4 acc[4][4];
#pragma unroll
    for (int i = 0; i < 4; ++i)
#pragma unroll
        for (int j = 0; j < 4; ++j) acc[i][j] = (floatx4)0.f;

    const int c8 = (t & 3) * 8, r0 = t >> 2;
    for (int c0 = 0; c0 < C_; c0 += 32) {
#pragma unroll
        for (int p = 0; p < 2; ++p) {
            *reinterpret_cast<uint4*>(&As[r0 + 64 * p][c8]) =
                *reinterpret_cast<const uint4*>(&Wm[(size_t)(ob + r0 + 64 * p) * C_ + c0 + c8]);
            *reinterpret_cast<uint4*>(&Bs[r0 + 64 * p][c8]) =
                *reinterpret_cast<const uint4*>(&xT[((size_t)b * L_ + lb + r0 + 64 * p) * C_ + c0 + c8]);
        }
        __syncthreads();

        short8 a[4], bb[4];
#pragma unroll
        for (int mt = 0; mt < 4; ++mt)
            a[mt] = *reinterpret_cast<const short8*>(&As[wm * 64 + mt * 16 + lc][quad * 8]);
#pragma unroll
        for (int nt = 0; nt < 4; ++nt)
            bb[nt] = *reinterpret_cast<const short8*>(&Bs[wn * 64 + nt * 16 + lc][quad * 8]);
#pragma unroll
        for (int mt = 0; mt < 4; ++mt)
#pragma unroll
            for (int nt = 0; nt < 4; ++nt)
                acc[mt][nt] = __builtin_amdgcn_mfma_f32_16x16x32_bf16(a[mt], bb[nt], acc[mt][nt], 0, 0, 0);
        __syncthreads();
    }

    const float scale = (mat == 0) ? 0.125f : 1.0f;
    unsigned short* dst = (mat == 0) ? Qc : ((mat == 1) ? Kc : Vc);
#pragma unroll
    for (int mt = 0; mt < 4; ++mt) {
#pragma unroll
        for (int r = 0; r < 4; ++r) {
            const int o  = ob + wm * 64 + mt * 16 + quad * 4 + r;
            const float bi = bqkv[mat * 512 + o];
#pragma unroll
            for (int nt = 0; nt < 4; ++nt) {
                const int l = lb + wn * 64 + nt * 16 + lc;
                const float val = (acc[mt][nt][r] + bi) * scale;
                dst[((size_t)b * C_ + o) * L_ + l] =
                    (mat == 2) ? f2h(val) : f2bf(val);
            }
        }
    }
}

// ---------------------------------------------------------------------------
// K transpose: Kc bf16 (B,C,L) -> Kb bf16 (B,H,L,Dh).  64x64 LDS tiles.
// ---------------------------------------------------------------------------
__global__ __launch_bounds__(256) void ktrans_kernel(
    const unsigned short* __restrict__ Kc, unsigned short* __restrict__ Kb)
{
    __shared__ unsigned short tile[64][72];
    const int jt = blockIdx.x;   // 16
    const int bh = blockIdx.y;   // 64
    const int b = bh >> 3, h = bh & 7;
    const int t = threadIdx.x;
    const size_t cBase = ((size_t)b * C_ + h * DH) * L_;
    const int j0 = jt * 64;
    {
        const int d = t >> 2, j8 = (t & 3) * 8;
#pragma unroll
        for (int p = 0; p < 2; ++p)
            *reinterpret_cast<uint4*>(&tile[d][j8 + 32 * p]) =
                *reinterpret_cast<const uint4*>(&Kc[cBase + (size_t)d * L_ + j0 + j8 + 32 * p]);
    }
    __syncthreads();
    {
        const int j = t >> 2, ds = (t & 3) * 16;
        union { unsigned short u[8]; uint4 q; } v0, v1;
#pragma unroll
        for (int i = 0; i < 8; ++i) v0.u[i] = tile[ds + i][j];
#pragma unroll
        for (int i = 0; i < 8; ++i) v1.u[i] = tile[ds + 8 + i][j];
        const size_t o = ((size_t)bh * L_ + j0 + j) * DH + ds;
        *reinterpret_cast<uint4*>(&Kb[o])     = v0.q;
        *reinterpret_cast<uint4*>(&Kb[o + 8]) = v1.q;
    }
}

// ---------------------------------------------------------------------------
// Attention v5: S^T formulation — P never leaves registers.
//   S^T = K·Q^T via mfma_16x16x32_bf16(A=K-frag, B=Q-frag):
//     C/D layout (row=quad*4+r -> j, col=lc -> l) == B-operand layout of
//     mfma_f32_16x16x16_f16 (n=lc, k=quad*4+i).  exp(S^T) in-register is
//     the PV B-fragment: O^T = V^T·P^T, A = V^T-frags (ds_read_b64 from
//     vst[d][j]).  No P round-trip, no rowsum MFMA (scalar adds + 2 shfl).
// 512 blocks (bh 64 x rt 8; id%8==h -> XCD L2 locality), 4 waves x 32 rows.
// K/V double-buffered in LDS (one barrier/tile), V and P in f16.
// ---------------------------------------------------------------------------
__global__ __launch_bounds__(256) void attn_kernel5(
    const unsigned short* __restrict__ Qc,   // bf16 (B,C,L), pre-scaled
    const unsigned short* __restrict__ Kb,   // bf16 (B,H,L,Dh)
    const unsigned short* __restrict__ Vc,   // f16  (B,C,L)
    const float* __restrict__ erel_k, const float* __restrict__ erel_v,
    unsigned short* __restrict__ AOh, unsigned short* __restrict__ AOl)
{
    __shared__ __align__(16) unsigned short kst[2][64][72];  // [buf][j][d] bf16
    __shared__ __align__(16) unsigned short vst[2][64][72];  // [buf][d][j] f16
    __shared__ float rs[128][9];
    __shared__ float rv[128][9];
    __shared__ float ervs[9][64];

    const int t  = threadIdx.x;
    const int bh = blockIdx.x;          // 0..63
    const int rt = blockIdx.y;          // 0..7
    const int b = bh >> 3, h = bh & 7;
    const int w = t >> 6, lane = t & 63, quad = lane >> 4, lc = lane & 15;
    const int row0 = rt * 128;
    const int rowW = row0 + w * 32;

    const size_t qkBase = (size_t)bh * L_ * DH;          // Kb
    const size_t cBase  = ((size_t)b * C_ + h * DH) * L_; // Qc/Vc

    for (int i = t; i < 9 * 64; i += 256) ervs[i / 64][i % 64] = erel_v[i];
    for (int i = lane; i < 32 * 9; i += 64) rv[w * 32 + i / 9][i % 9] = 0.f;

    // Q B-fragments (one-time scalar gather from (B,C,L))
    short8 af[2][2];
#pragma unroll
    for (int rg = 0; rg < 2; ++rg)
#pragma unroll
        for (int kk = 0; kk < 2; ++kk) {
            short8 q;
#pragma unroll
            for (int i = 0; i < 8; ++i) {
                const int d = kk * 32 + quad * 8 + i;
                q[i] = (short)Qc[cBase + (size_t)d * L_ + rowW + rg * 16 + lc];
            }
            af[rg][kk] = q;
        }

    // rel-k scores: D[dr][l] = erk . Q^T  (C row=dr, col=l)
#pragma unroll
    for (int rg = 0; rg < 2; ++rg) {
        floatx4 rsa = (floatx4)0.f;
        const int drow = (lc < 9) ? lc : 8;
#pragma unroll
        for (int kk = 0; kk < 2; ++kk) {
            short8 ea;
#pragma unroll
            for (int i = 0; i < 8; ++i)
                ea[i] = (short)f2bf(erel_k[drow * 64 + kk * 32 + quad * 8 + i]);
            rsa = __builtin_amdgcn_mfma_f32_16x16x32_bf16(ea, af[rg][kk], rsa, 0, 0, 0);
        }
#pragma unroll
        for (int r = 0; r < 4; ++r) {
            const int dr = quad * 4 + r;
            if (dr < 9) rs[w * 32 + rg * 16 + lc][dr] = rsa[r];
        }
    }

    // stage tile 0
    const int jr = t >> 3, jc = (t & 7) * 8;
#pragma unroll
    for (int p = 0; p < 2; ++p) {
        *reinterpret_cast<uint4*>(&kst[0][jr + 32 * p][jc]) =
            *reinterpret_cast<const uint4*>(&Kb[qkBase + (size_t)(jr + 32 * p) * DH + jc]);
        *reinterpret_cast<uint4*>(&vst[0][jr + 32 * p][jc]) =
            *reinterpret_cast<const uint4*>(&Vc[cBase + (size_t)(jr + 32 * p) * L_ + jc]);
    }
    __syncthreads();

    floatx4 accT[2][4];
    float lsum[2] = {0.f, 0.f};
#pragma unroll
    for (int rg = 0; rg < 2; ++rg)
#pragma unroll
        for (int dc = 0; dc < 4; ++dc) accT[rg][dc] = (floatx4)0.f;

    for (int jt = 0; jt < L_ / 64; ++jt) {
        const int j0  = jt * 64;
        const int cur = jt & 1;

        // register prefetch of next K/V tile
        uint4 pk[2], pv[2];
        if (jt < L_ / 64 - 1) {
            const int j0n = j0 + 64;
#pragma unroll
            for (int p = 0; p < 2; ++p) {
                pk[p] = *reinterpret_cast<const uint4*>(
                    &Kb[qkBase + (size_t)(j0n + jr + 32 * p) * DH + jc]);
                pv[p] = *reinterpret_cast<const uint4*>(
                    &Vc[cBase + (size_t)(jr + 32 * p) * L_ + j0n + jc]);
            }
        }

        // hoisted fragment loads (shared by both row-groups)
        short8 kf[4][2];
#pragma unroll
        for (int nt = 0; nt < 4; ++nt)
#pragma unroll
            for (int kk = 0; kk < 2; ++kk)
                kf[nt][kk] = *reinterpret_cast<const short8*>(
                    &kst[cur][nt * 16 + lc][kk * 32 + quad * 8]);
        half4_ vf[4][4];
#pragma unroll
        for (int dc = 0; dc < 4; ++dc)
#pragma unroll
            for (int nk = 0; nk < 4; ++nk)
                vf[dc][nk] = *reinterpret_cast<const half4_*>(
                    &vst[cur][dc * 16 + lc][nk * 16 + quad * 4]);

#pragma unroll
        for (int rg = 0; rg < 2; ++rg) {
            const int rowWg = rowW + rg * 16;
            const int lg    = rowWg + lc;        // this lane's l (column)

            // S^T = K Q^T
            floatx4 sacc[4];
#pragma unroll
            for (int nt = 0; nt < 4; ++nt) sacc[nt] = (floatx4)0.f;
#pragma unroll
            for (int nt = 0; nt < 4; ++nt)
#pragma unroll
                for (int kk = 0; kk < 2; ++kk)
                    sacc[nt] = __builtin_amdgcn_mfma_f32_16x16x32_bf16(
                        kf[nt][kk], af[rg][kk], sacc[nt], 0, 0, 0);

            const bool nearD = (j0 <= rowWg + 15 + WIN) && (j0 + 63 >= rowWg - WIN);
            if (nearD) {
#pragma unroll
                for (int nt = 0; nt < 4; ++nt)
#pragma unroll
                    for (int r = 0; r < 4; ++r) {
                        const int diff = (j0 + nt * 16 + quad * 4 + r) - lg;
                        if (diff >= -WIN && diff <= WIN)
                            sacc[nt][r] += rs[w * 32 + rg * 16 + lc][diff + WIN];
                    }
            }

            // exp -> P^T fragments (f16) directly; scalar row-sum partials
            half4_ pf[4];
#pragma unroll
            for (int nt = 0; nt < 4; ++nt) {
#pragma unroll
                for (int r = 0; r < 4; ++r) {
                    const float p = __expf(sacc[nt][r]);
                    lsum[rg] += p;
                    pf[nt][r] = (_Float16)p;
                    if (nearD) {
                        const int diff = (j0 + nt * 16 + quad * 4 + r) - lg;
                        if (diff >= -WIN && diff <= WIN) {
                            const int rloc = w * 32 + rg * 16 + lc;
                            rv[rloc][diff + WIN] += p;   // unique (l,j) per lane
                        }
                    }
                }
            }

            // O^T += V^T P^T  (16x16x16 f16; pf IS the B-operand)
#pragma unroll
            for (int dc = 0; dc < 4; ++dc)
#pragma unroll
                for (int nk = 0; nk < 4; ++nk)
                    accT[rg][dc] = __builtin_amdgcn_mfma_f32_16x16x16f16(
                        vf[dc][nk], pf[nk], accT[rg][dc], 0, 0, 0);
        }

        if (jt < L_ / 64 - 1) {
#pragma unroll
            for (int p = 0; p < 2; ++p) {
                *reinterpret_cast<uint4*>(&kst[1 - cur][jr + 32 * p][jc]) = pk[p];
                *reinterpret_cast<uint4*>(&vst[1 - cur][jr + 32 * p][jc]) = pv[p];
            }
        }
        __syncthreads();
    }

    // epilogue: O^T lane holds l=lc, d=dc*16+quad*4+r (4 consecutive d!)
#pragma unroll
    for (int rg = 0; rg < 2; ++rg) {
        float s = lsum[rg];
        s += __shfl_xor(s, 16);
        s += __shfl_xor(s, 32);
        const float inv = 1.f / s;
        const int rloc = w * 32 + rg * 16 + lc;
        float rvr[9];
#pragma unroll
        for (int dr = 0; dr < 9; ++dr) rvr[dr] = rv[rloc][dr];
#pragma unroll
        for (int dc = 0; dc < 4; ++dc) {
            ushort4 sh, sl;
            float ov[4];
#pragma unroll
            for (int r = 0; r < 4; ++r) {
                const int d = dc * 16 + quad * 4 + r;
                float v = accT[rg][dc][r];
#pragma unroll
                for (int dr = 0; dr < 9; ++dr) v += rvr[dr] * ervs[dr][d];
                ov[r] = v * inv;
            }
            sh.x = f2bf(ov[0]); sh.y = f2bf(ov[1]); sh.z = f2bf(ov[2]); sh.w = f2bf(ov[3]);
            sl.x = f2bf(ov[0] - bf2f(sh.x)); sl.y = f2bf(ov[1] - bf2f(sh.y));
            sl.z = f2bf(ov[2] - bf2f(sh.z)); sl.w = f2bf(ov[3] - bf2f(sh.w));
            const size_t idx = ((size_t)b * L_ + row0 + rloc) * C_ + h * 64 + dc * 16 + quad * 4;
            *reinterpret_cast<ushort4*>(&AOh[idx]) = sh;
            *reinterpret_cast<ushort4*>(&AOl[idx]) = sl;
        }
    }
}

// ---------------------------------------------------------------------------
// Output projection, 3-term hi/lo split.  M=512 x N-tile 64 x K=512.
// ---------------------------------------------------------------------------
__global__ __launch_bounds__(256) void out_gemm_kernel(
    const unsigned short* __restrict__ Wh, const unsigned short* __restrict__ Wl,
    const float* __restrict__ bo,
    const unsigned short* __restrict__ Ah, const unsigned short* __restrict__ Al,
    float* __restrict__ Y)
{
    __shared__ __align__(16) unsigned short As_h[128][40];
    __shared__ __align__(16) unsigned short As_l[128][40];
    __shared__ __align__(16) unsigned short Bs_h[64][40];
    __shared__ __align__(16) unsigned short Bs_l[64][40];

    const int b  = blockIdx.z;
    const int ob = blockIdx.y * 128;
    const int lb = blockIdx.x * 64;
    const int t  = threadIdx.x;
    const int w = t >> 6, lane = t & 63, quad = lane >> 4, lc = lane & 15;
    const int wm = w >> 1, wn = w & 1;

    floatx4 acc[4][2];
#pragma unroll
    for (int i = 0; i < 4; ++i)
#pragma unroll
        for (int j = 0; j < 2; ++j) acc[i][j] = (floatx4)0.f;

    const int c8 = (t & 3) * 8, r0 = t >> 2;
    for (int c0 = 0; c0 < C_; c0 += 32) {
#pragma unroll
        for (int p = 0; p < 2; ++p) {
            *reinterpret_cast<uint4*>(&As_h[r0 + 64 * p][c8]) =
                *reinterpret_cast<const uint4*>(&Wh[(size_t)(ob + r0 + 64 * p) * C_ + c0 + c8]);
            *reinterpret_cast<uint4*>(&As_l[r0 + 64 * p][c8]) =
                *reinterpret_cast<const uint4*>(&Wl[(size_t)(ob + r0 + 64 * p) * C_ + c0 + c8]);
        }
        {
            const size_t g = ((size_t)b * L_ + lb + r0) * C_ + c0 + c8;
            *reinterpret_cast<uint4*>(&Bs_h[r0][c8]) =
                *reinterpret_cast<const uint4*>(&Ah[g]);
            *reinterpret_cast<uint4*>(&Bs_l[r0][c8]) =
                *reinterpret_cast<const uint4*>(&Al[g]);
        }
        __syncthreads();

        short8 ah[4], al[4], bhf[2], blf[2];
#pragma unroll
        for (int mt = 0; mt < 4; ++mt) {
            const int row = wm * 64 + mt * 16 + lc;
            ah[mt] = *reinterpret_cast<const short8*>(&As_h[row][quad * 8]);
            al[mt] = *reinterpret_cast<const short8*>(&As_l[row][quad * 8]);
        }
#pragma unroll
        for (int nt = 0; nt < 2; ++nt) {
            const int row = wn * 32 + nt * 16 + lc;
            bhf[nt] = *reinterpret_cast<const short8*>(&Bs_h[row][quad * 8]);
            blf[nt] = *reinterpret_cast<const short8*>(&Bs_l[row][quad * 8]);
        }
#pragma unroll
        for (int mt = 0; mt < 4; ++mt)
#pragma unroll
            for (int nt = 0; nt < 2; ++nt) {
                acc[mt][nt] = __builtin_amdgcn_mfma_f32_16x16x32_bf16(ah[mt], bhf[nt], acc[mt][nt], 0, 0, 0);
                acc[mt][nt] = __builtin_amdgcn_mfma_f32_16x16x32_bf16(ah[mt], blf[nt], acc[mt][nt], 0, 0, 0);
                acc[mt][nt] = __builtin_amdgcn_mfma_f32_16x16x32_bf16(al[mt], bhf[nt], acc[mt][nt], 0, 0, 0);
            }
        __syncthreads();
    }

#pragma unroll
    for (int mt = 0; mt < 4; ++mt) {
#pragma unroll
        for (int r = 0; r < 4; ++r) {
            const int o = ob + wm * 64 + mt * 16 + quad * 4 + r;
            const float bi = bo[o];
#pragma unroll
            for (int nt = 0; nt < 2; ++nt) {
                const int l = lb + wn * 32 + nt * 16 + lc;
                Y[((size_t)b * C_ + o) * L_ + l] = acc[mt][nt][r] + bi;
            }
        }
    }
}

// ---------------------------------------------------------------------------
extern "C" void kernel_launch(void* const* d_in, const int* in_sizes, int n_in,
                              void* d_out, int out_size, void* d_ws, size_t ws_size,
                              hipStream_t stream)
{
    const float* x   = (const float*)d_in[0];
    const float* Wq  = (const float*)d_in[1];
    const float* bq  = (const float*)d_in[2];
    const float* Wk  = (const float*)d_in[3];
    const float* bk  = (const float*)d_in[4];
    const float* Wv  = (const float*)d_in[5];
    const float* bv  = (const float*)d_in[6];
    const float* Wo  = (const float*)d_in[7];
    const float* bo  = (const float*)d_in[8];
    const float* erk = (const float*)d_in[9];
    const float* erv = (const float*)d_in[10];

    char* ws = (char*)d_ws;
    const size_t MB = 1024u * 1024u;
    unsigned short* xT      = (unsigned short*)(ws);             // 8 MB
    unsigned short* Qc      = (unsigned short*)(ws + 8 * MB);    // 8 MB bf16 (B,C,L)
    unsigned short* Kc      = (unsigned short*)(ws + 16 * MB);   // 8 MB bf16 (B,C,L)
    unsigned short* Vc      = (unsigned short*)(ws + 24 * MB);   // 8 MB f16  (B,C,L)
    unsigned short* Kb      = (unsigned short*)(ws + 32 * MB);   // 8 MB bf16 (B,H,L,Dh)
    unsigned short* AOh     = (unsigned short*)(ws + 40 * MB);   // 8 MB
    unsigned short* AOl     = (unsigned short*)(ws + 48 * MB);   // 8 MB
    unsigned short* Wqkv_hi = (unsigned short*)(ws + 56 * MB);   // 1.5 MB
    unsigned short* Wo_hi   = (unsigned short*)(ws + 58 * MB);   // 0.5 MB
    unsigned short* Wo_lo   = (unsigned short*)(ws + 59 * MB);   // 0.5 MB
    float*          bqkv    = (float*)(ws + 60 * MB);            // 6 KB

    prep_kernel<<<256, 256, 0, stream>>>(Wq, Wk, Wv, Wo, bq, bk, bv,
                                         Wqkv_hi, Wo_hi, Wo_lo, bqkv);
    transpose_kernel<<<dim3(L_ / 32, C_ / 32, B_), 256, 0, stream>>>(x, xT);
    qkv_gemm_kernel<<<dim3(L_ / 128, 12, B_), 256, 0, stream>>>(
        Wqkv_hi, bqkv, xT, Qc, Kc, Vc);
    ktrans_kernel<<<dim3(16, 64), 256, 0, stream>>>(Kc, Kb);
    attn_kernel5<<<dim3(64, 8), 256, 0, stream>>>(
        Qc, Kb, Vc, erk, erv, AOh, AOl);
    out_gemm_kernel<<<dim3(L_ / 64, C_ / 128, B_), 256, 0, stream>>>(
        Wo_hi, Wo_lo, bo, AOh, AOl, (float*)d_out);
}